// Round 4
// baseline (187.207 us; speedup 1.0000x reference)
//
#include <hip/hip_runtime.h>
#include <cstdint>

#define NXC 768
#define NHEAD 12
#define BB 2
#define SS 2048
#define MTOT (BB*SS)        // 4096
#define NQKV (3*NXC)        // 2304
#define PRESENT_HALF (BB*NHEAD*SS*64)   // 3145728

typedef __bf16 bf16x8 __attribute__((ext_vector_type(8)));
typedef float f32x4 __attribute__((ext_vector_type(4)));
typedef float f32x16 __attribute__((ext_vector_type(16)));

__device__ __forceinline__ uint16_t f2bf(float f) {
    uint32_t u = __builtin_bit_cast(uint32_t, f);
    uint32_t r = (u + 0x7FFFu + ((u >> 16) & 1u)) >> 16;
    return (uint16_t)r;
}

__device__ __forceinline__ bf16x8 vfrag(ushort4 a, ushort4 b) {
    union { bf16x8 v; ushort4 u[2]; } r;
    r.u[0] = a; r.u[1] = b;
    return r.v;
}

// async global->LDS, 16B per lane; lds dest = wave-uniform base + lane*16
__device__ __forceinline__ void gload16(const uint16_t* g, uint16_t* l) {
    __builtin_amdgcn_global_load_lds(
        (const __attribute__((address_space(1))) unsigned int*)g,
        (__attribute__((address_space(3))) unsigned int*)l, 16, 0, 0);
}

// ---------------- prep kernels ----------------

__global__ void prep_x(const float* __restrict__ in, uint16_t* __restrict__ out) {
    int i = blockIdx.x * 256 + threadIdx.x;
    float4 v = ((const float4*)in)[i];
    ushort4 o;
    o.x = f2bf(v.x); o.y = f2bf(v.y); o.z = f2bf(v.z); o.w = f2bf(v.w);
    ((ushort4*)out)[i] = o;
}

__global__ void prep_weff(const float* __restrict__ w_attn,
                          const float* __restrict__ lora_A,
                          const float* __restrict__ lora_B,
                          uint16_t* __restrict__ weffT) {
    int i = blockIdx.x * 256 + threadIdx.x;
    int n = i / NXC, k = i - n * NXC;
    int c = n / NXC;
    float acc = w_attn[(size_t)k * NQKV + n];
    float d = 0.f;
#pragma unroll
    for (int r = 0; r < 8; ++r)
        d += lora_A[(size_t)(c * 8 + r) * NXC + k] * lora_B[(size_t)n * 8 + r];
    weffT[(size_t)n * NXC + k] = f2bf(acc + 16.0f * d);
}

__global__ void prep_wproj(const float* __restrict__ w_proj, uint16_t* __restrict__ wpT) {
    int i = blockIdx.x * 256 + threadIdx.x;
    int n = i / NXC, k = i - n * NXC;
    wpT[(size_t)n * NXC + k] = f2bf(w_proj[(size_t)k * NXC + n]);
}

// ---------------- GEMM: C = A[M,768] * BT[N,768]^T, global_load_lds staging ----------------

template<int MODE>
__global__ __launch_bounds__(256) void gemm_bt(
    const uint16_t* __restrict__ Abf, const uint16_t* __restrict__ BTbf,
    const float* __restrict__ bias, float* __restrict__ outf,
    uint16_t* __restrict__ q_bf, uint16_t* __restrict__ k_bf,
    uint16_t* __restrict__ vT_bf) {
    __shared__ uint16_t As[128][32];
    __shared__ uint16_t Bs[128][32];
    const int t = threadIdx.x;
    const int lane = t & 63;
    const int w = t >> 6;
    const int wr = (w >> 1) * 64;
    const int wc = (w & 1) * 64;
    const int lr16 = lane & 15;
    const int lk = (lane >> 4) << 3;
    const size_t arow0 = (size_t)blockIdx.y * 128;
    const size_t brow0 = (size_t)blockIdx.x * 128;
    // staging: wave w, instr i stages rows [(i*4+w)*16, +16); lane: row += lane>>2, col (lane&3)*8
    const int sr = lane >> 2;
    const int sc = (lane & 3) * 8;
    const uint16_t* Ap0 = Abf + (arow0 + w * 16 + sr) * NXC + sc;
    const uint16_t* Ap1 = Abf + (arow0 + 64 + w * 16 + sr) * NXC + sc;
    const uint16_t* Bp0 = BTbf + (brow0 + w * 16 + sr) * NXC + sc;
    const uint16_t* Bp1 = BTbf + (brow0 + 64 + w * 16 + sr) * NXC + sc;
    uint16_t* lA0 = &As[w * 16][0];
    uint16_t* lA1 = &As[64 + w * 16][0];
    uint16_t* lB0 = &Bs[w * 16][0];
    uint16_t* lB1 = &Bs[64 + w * 16][0];

    f32x4 acc[4][4];
#pragma unroll
    for (int m = 0; m < 4; ++m)
#pragma unroll
        for (int n = 0; n < 4; ++n) acc[m][n] = (f32x4){0.f, 0.f, 0.f, 0.f};

    for (int kt = 0; kt < 24; ++kt) {
        const int k0 = kt << 5;
        gload16(Ap0 + k0, lA0);
        gload16(Ap1 + k0, lA1);
        gload16(Bp0 + k0, lB0);
        gload16(Bp1 + k0, lB1);
        asm volatile("s_waitcnt vmcnt(0)" ::: "memory");
        __syncthreads();
        bf16x8 af[4], bv[4];
#pragma unroll
        for (int m = 0; m < 4; ++m) af[m] = *(const bf16x8*)&As[wr + m * 16 + lr16][lk];
#pragma unroll
        for (int n = 0; n < 4; ++n) bv[n] = *(const bf16x8*)&Bs[wc + n * 16 + lr16][lk];
#pragma unroll
        for (int m = 0; m < 4; ++m)
#pragma unroll
            for (int n = 0; n < 4; ++n)
                acc[m][n] = __builtin_amdgcn_mfma_f32_16x16x32_bf16(af[m], bv[n], acc[m][n], 0, 0, 0);
        __syncthreads();
    }

    const int rowb = (lane >> 4) << 2;
    const float QSCALE = 0.125f * 1.44269504f;   // fold 1/sqrt(dh) and log2(e)
#pragma unroll
    for (int m = 0; m < 4; ++m) {
        int grow0 = (int)arow0 + wr + m * 16 + rowb;
#pragma unroll
        for (int n = 0; n < 4; ++n) {
            int gcol = (int)brow0 + wc + n * 16 + lr16;
            float bvs = bias[gcol];
            if (MODE == 1) {
#pragma unroll
                for (int ri = 0; ri < 4; ++ri) {
                    int grow = grow0 + ri;
                    outf[(size_t)grow * NXC + gcol] = acc[m][n][ri] + bvs;
                }
            } else {
                int c = gcol >= 2 * NXC ? 2 : (gcol >= NXC ? 1 : 0);
                int e = gcol - c * NXC;
                int h = e >> 6, d = e & 63;
#pragma unroll
                for (int ri = 0; ri < 4; ++ri) {
                    int grow = grow0 + ri;
                    int b = grow >> 11, s = grow & 2047;
                    float v = acc[m][n][ri] + bvs;
                    size_t hidx = ((size_t)(b * NHEAD + h) * SS + s);
                    if (c == 0) {
                        q_bf[hidx * 64 + d] = f2bf(v * QSCALE);
                    } else if (c == 1) {
                        k_bf[hidx * 64 + d] = f2bf(v);
                        outf[hidx * 64 + d] = v;
                    } else {
                        vT_bf[((size_t)(b * NHEAD + h) * 64 + d) * SS + s] = f2bf(v);
                        outf[PRESENT_HALF + hidx * 64 + d] = v;
                    }
                }
            }
        }
    }
}

// ---------------- flash attention ----------------
// grid 1536, block 128 (2 waves). Block = one 32-row q-group; wave w takes 32-key
// tiles w, w+2, ... (even/odd split), 2-deep pipeline (QK of t+2 overlaps softmax/PV
// of t). Scores in log2 domain (0.125*log2e folded into q_bf). 2-way LDS merge.

__global__ __launch_bounds__(128, 3) void attn_kernel(
    const uint16_t* __restrict__ qb, const uint16_t* __restrict__ kb,
    const uint16_t* __restrict__ vtb, uint16_t* __restrict__ ab) {
    __shared__ float Ml[2][32];
    __shared__ float Ll[2][32];
    __shared__ float Ol[2][64][33];
    const int t = threadIdx.x;
    const int w = t >> 6, lane = t & 63;
    const int l31 = lane & 31, hi = lane >> 5;
    const int id = blockIdx.x;
    const int xcd = id & 7, slot = id >> 3;
    const int lh = slot >> 6, qslot = slot & 63;
    const int qi = 63 - qslot;            // heavy q-groups dispatch first
    const int bh = xcd * 3 + lh;          // 3 heads per XCD -> K/V L2 resident
    const int qbase = qi * 32;
    const uint16_t* qh = qb + (size_t)bh * (SS * 64);
    const uint16_t* kh = kb + (size_t)bh * (SS * 64);
    const uint16_t* vh = vtb + (size_t)bh * (64 * SS);
    const int q = qbase + l31;
    const float L2E = 1.44269504f;
    const int nkt = (qbase >> 5) + 1;     // 32-key tiles, last one is the diagonal

    bf16x8 qf[4];
#pragma unroll
    for (int dc = 0; dc < 4; ++dc)
        qf[dc] = *(const bf16x8*)(qh + (size_t)q * 64 + dc * 16 + hi * 8);

    f32x16 o0, o1;
#pragma unroll
    for (int i = 0; i < 16; ++i) { o0[i] = 0.f; o1[i] = 0.f; }
    float m_run = -1e30f, l_run = 0.f;

    // prologue: scores for first tile, K-frags for second
    const int c0 = (w < nkt) ? w : (nkt - 1);
    f32x16 s_cur;
#pragma unroll
    for (int i = 0; i < 16; ++i) s_cur[i] = 0.f;
    {
        const uint16_t* p0 = kh + (size_t)(c0 * 32 + l31) * 64 + hi * 8;
        bf16x8 kf0 = *(const bf16x8*)(p0);
        bf16x8 kf1 = *(const bf16x8*)(p0 + 16);
        bf16x8 kf2 = *(const bf16x8*)(p0 + 32);
        bf16x8 kf3 = *(const bf16x8*)(p0 + 48);
        s_cur = __builtin_amdgcn_mfma_f32_32x32x16_bf16(kf0, qf[0], s_cur, 0, 0, 0);
        s_cur = __builtin_amdgcn_mfma_f32_32x32x16_bf16(kf1, qf[1], s_cur, 0, 0, 0);
        s_cur = __builtin_amdgcn_mfma_f32_32x32x16_bf16(kf2, qf[2], s_cur, 0, 0, 0);
        s_cur = __builtin_amdgcn_mfma_f32_32x32x16_bf16(kf3, qf[3], s_cur, 0, 0, 0);
    }
    bf16x8 ka[4];
    {
        const int c1 = (w + 2 < nkt) ? (w + 2) : (nkt - 1);
        const uint16_t* p0 = kh + (size_t)(c1 * 32 + l31) * 64 + hi * 8;
#pragma unroll
        for (int dc = 0; dc < 4; ++dc) ka[dc] = *(const bf16x8*)(p0 + dc * 16);
    }

    for (int tt = w; tt < nkt; tt += 2) {
        const int kbase = tt << 5;
        // V loads for this tile: cv[dblk*4 + kh2*2 + part]
        ushort4 cv[8];
#pragma unroll
        for (int dblk = 0; dblk < 2; ++dblk) {
            const uint16_t* p0 = vh + (size_t)(dblk * 32 + l31) * SS + kbase + hi * 4;
            cv[dblk * 4 + 0] = *(const ushort4*)(p0);
            cv[dblk * 4 + 1] = *(const ushort4*)(p0 + 8);
            cv[dblk * 4 + 2] = *(const ushort4*)(p0 + 16);
            cv[dblk * 4 + 3] = *(const ushort4*)(p0 + 24);
        }
        // next scores (tile tt+2) -- overlaps with softmax/PV below
        f32x16 s_n;
#pragma unroll
        for (int i = 0; i < 16; ++i) s_n[i] = 0.f;
        s_n = __builtin_amdgcn_mfma_f32_32x32x16_bf16(ka[0], qf[0], s_n, 0, 0, 0);
        s_n = __builtin_amdgcn_mfma_f32_32x32x16_bf16(ka[1], qf[1], s_n, 0, 0, 0);
        s_n = __builtin_amdgcn_mfma_f32_32x32x16_bf16(ka[2], qf[2], s_n, 0, 0, 0);
        s_n = __builtin_amdgcn_mfma_f32_32x32x16_bf16(ka[3], qf[3], s_n, 0, 0, 0);
        // reload ka with tile tt+4 (consumed next iteration)
        {
            const int cn = (tt + 4 < nkt) ? (tt + 4) : (nkt - 1);
            const uint16_t* p0 = kh + (size_t)(cn * 32 + l31) * 64 + hi * 8;
#pragma unroll
            for (int dc = 0; dc < 4; ++dc) ka[dc] = *(const bf16x8*)(p0 + dc * 16);
        }
        // causal mask (diagonal tile only); key(r) = (r&3) + 8*(r>>2) + 4*hi
        if (kbase == qbase) {
            const int qrel = l31;
#pragma unroll
            for (int r = 0; r < 16; ++r) {
                int key = (r & 3) + 8 * (r >> 2) + 4 * hi;
                s_cur[r] = (key > qrel) ? -1e30f : s_cur[r];
            }
        }
        // row max: pairwise tree + one cross-half exchange
        float mx4[4];
#pragma unroll
        for (int g = 0; g < 4; ++g)
            mx4[g] = fmaxf(fmaxf(s_cur[g * 4], s_cur[g * 4 + 1]),
                           fmaxf(s_cur[g * 4 + 2], s_cur[g * 4 + 3]));
        float tm = fmaxf(fmaxf(mx4[0], mx4[1]), fmaxf(mx4[2], mx4[3]));
        tm = fmaxf(tm, __shfl_xor(tm, 32));
        // defer-max (log2 domain)
        if (__any(tm > m_run + 8.f)) {
            float nm = fmaxf(m_run, tm);
            float corr = __builtin_amdgcn_exp2f(m_run - nm);
            l_run *= corr;
#pragma unroll
            for (int i = 0; i < 16; ++i) { o0[i] *= corr; o1[i] *= corr; }
            m_run = nm;
        }
        // exp (scores already in log2 domain) + bf16 pack + sum tree
        float e[16];
#pragma unroll
        for (int r = 0; r < 16; ++r) e[r] = __builtin_amdgcn_exp2f(s_cur[r] - m_run);
        bf16x8 pa0, pa1;
#pragma unroll
        for (int r = 0; r < 8; ++r) { pa0[r] = (__bf16)e[r]; pa1[r] = (__bf16)e[8 + r]; }
        float sp0 = (e[0] + e[1]) + (e[2] + e[3]);
        float sp1 = (e[4] + e[5]) + (e[6] + e[7]);
        float sp2 = (e[8] + e[9]) + (e[10] + e[11]);
        float sp3 = (e[12] + e[13]) + (e[14] + e[15]);
        float ps = (sp0 + sp1) + (sp2 + sp3);
        ps += __shfl_xor(ps, 32);
        l_run += ps;
        // PV: O^T[d][q] += V^T-frag x P-frag (same key permutation both sides)
        o0 = __builtin_amdgcn_mfma_f32_32x32x16_bf16(vfrag(cv[0], cv[1]), pa0, o0, 0, 0, 0);
        o0 = __builtin_amdgcn_mfma_f32_32x32x16_bf16(vfrag(cv[2], cv[3]), pa1, o0, 0, 0, 0);
        o1 = __builtin_amdgcn_mfma_f32_32x32x16_bf16(vfrag(cv[4], cv[5]), pa0, o1, 0, 0, 0);
        o1 = __builtin_amdgcn_mfma_f32_32x32x16_bf16(vfrag(cv[6], cv[7]), pa1, o1, 0, 0, 0);
        s_cur = s_n;
    }

    // ---- write partials + 2-way merge ----
    if (hi == 0) { Ml[w][l31] = m_run; Ll[w][l31] = l_run; }
#pragma unroll
    for (int r = 0; r < 16; ++r) {
        int d = (r & 3) + 8 * (r >> 2) + 4 * hi;
        Ol[w][d][l31] = o0[r];
        Ol[w][32 + d][l31] = o1[r];
    }
    __syncthreads();

    const int tq = t >> 2, dblk = t & 3;
    float m0 = Ml[0][tq], m1 = Ml[1][tq];
    float M = fmaxf(m0, m1);
    float w0 = __builtin_amdgcn_exp2f(m0 - M);
    float w1 = __builtin_amdgcn_exp2f(m1 - M);
    float ltot = w0 * Ll[0][tq] + w1 * Ll[1][tq];
    float inv = 1.f / ltot;
    float vals[16];
#pragma unroll
    for (int dd = 0; dd < 16; ++dd)
        vals[dd] = (w0 * Ol[0][dblk * 16 + dd][tq] + w1 * Ol[1][dblk * 16 + dd][tq]) * inv;
    const int b = bh / NHEAD, h = bh - b * NHEAD;
    uint16_t* abp = ab + (size_t)(b * SS + qbase + tq) * NXC + h * 64 + dblk * 16;
#pragma unroll
    for (int g = 0; g < 4; ++g) {
        ushort4 wv;
        wv.x = f2bf(vals[g * 4 + 0]);
        wv.y = f2bf(vals[g * 4 + 1]);
        wv.z = f2bf(vals[g * 4 + 2]);
        wv.w = f2bf(vals[g * 4 + 3]);
        *(ushort4*)(abp + g * 4) = wv;
    }
}

// ---------------- launch ----------------

extern "C" void kernel_launch(void* const* d_in, const int* in_sizes, int n_in,
                              void* d_out, int out_size, void* d_ws, size_t ws_size,
                              hipStream_t stream) {
    const float* x      = (const float*)d_in[0];
    const float* w_attn = (const float*)d_in[1];
    const float* b_attn = (const float*)d_in[2];
    const float* lora_A = (const float*)d_in[3];
    const float* lora_B = (const float*)d_in[4];
    const float* w_proj = (const float*)d_in[5];
    const float* b_proj = (const float*)d_in[6];
    float* out = (float*)d_out;
    float* present = out + (size_t)MTOT * NXC;   // 3145728

    uint16_t* ws    = (uint16_t*)d_ws;
    uint16_t* x_bf  = ws;                         // 3145728
    uint16_t* weffT = x_bf + 3145728;             // 1769472
    uint16_t* wpT   = weffT + 1769472;            // 589824
    uint16_t* q_bf  = wpT + 589824;               // 3145728
    uint16_t* k_bf  = q_bf + 3145728;             // 3145728
    uint16_t* vT_bf = k_bf + 3145728;             // 3145728
    uint16_t* a_bf  = vT_bf + 3145728;            // 3145728

    prep_x<<<dim3(3072), dim3(256), 0, stream>>>(x, x_bf);
    prep_weff<<<dim3(6912), dim3(256), 0, stream>>>(w_attn, lora_A, lora_B, weffT);
    prep_wproj<<<dim3(2304), dim3(256), 0, stream>>>(w_proj, wpT);

    gemm_bt<0><<<dim3(18, 32), dim3(256), 0, stream>>>(x_bf, weffT, b_attn, present,
                                                       q_bf, k_bf, vT_bf);
    attn_kernel<<<dim3(1536), dim3(128), 0, stream>>>(q_bf, k_bf, vT_bf, a_bf);
    gemm_bt<1><<<dim3(6, 32), dim3(256), 0, stream>>>(a_bf, wpT, b_proj, out,
                                                      nullptr, nullptr, nullptr);
}

// Round 5
// 129.714 us; speedup vs baseline: 1.4432x; 1.4432x over previous
//
#include <hip/hip_runtime.h>
#include <cstdint>

#define NXC 768
#define NHEAD 12
#define BB 2
#define SS 2048
#define MTOT (BB*SS)        // 4096
#define NQKV (3*NXC)        // 2304
#define PRESENT_HALF (BB*NHEAD*SS*64)   // 3145728

typedef __bf16 bf16x8 __attribute__((ext_vector_type(8)));
typedef float f32x4 __attribute__((ext_vector_type(4)));
typedef float f32x16 __attribute__((ext_vector_type(16)));

__device__ __forceinline__ uint16_t f2bf(float f) {
    uint32_t u = __builtin_bit_cast(uint32_t, f);
    uint32_t r = (u + 0x7FFFu + ((u >> 16) & 1u)) >> 16;
    return (uint16_t)r;
}

__device__ __forceinline__ bf16x8 vfrag(ushort4 a, ushort4 b) {
    union { bf16x8 v; ushort4 u[2]; } r;
    r.u[0] = a; r.u[1] = b;
    return r.v;
}

// async global->LDS, 16B per lane; lds dest = wave-uniform base + lane*16
__device__ __forceinline__ void gload16(const uint16_t* g, uint16_t* l) {
    __builtin_amdgcn_global_load_lds(
        (const __attribute__((address_space(1))) unsigned int*)g,
        (__attribute__((address_space(3))) unsigned int*)l, 16, 0, 0);
}

// ---------------- prep kernels ----------------

__global__ void prep_x(const float* __restrict__ in, uint16_t* __restrict__ out) {
    int i = blockIdx.x * 256 + threadIdx.x;
    float4 v = ((const float4*)in)[i];
    ushort4 o;
    o.x = f2bf(v.x); o.y = f2bf(v.y); o.z = f2bf(v.z); o.w = f2bf(v.w);
    ((ushort4*)out)[i] = o;
}

__global__ void prep_weff(const float* __restrict__ w_attn,
                          const float* __restrict__ lora_A,
                          const float* __restrict__ lora_B,
                          uint16_t* __restrict__ weffT) {
    int i = blockIdx.x * 256 + threadIdx.x;
    int n = i / NXC, k = i - n * NXC;
    int c = n / NXC;
    float acc = w_attn[(size_t)k * NQKV + n];
    float d = 0.f;
#pragma unroll
    for (int r = 0; r < 8; ++r)
        d += lora_A[(size_t)(c * 8 + r) * NXC + k] * lora_B[(size_t)n * 8 + r];
    weffT[(size_t)n * NXC + k] = f2bf(acc + 16.0f * d);
}

__global__ void prep_wproj(const float* __restrict__ w_proj, uint16_t* __restrict__ wpT) {
    int i = blockIdx.x * 256 + threadIdx.x;
    int n = i / NXC, k = i - n * NXC;
    wpT[(size_t)n * NXC + k] = f2bf(w_proj[(size_t)k * NXC + n]);
}

// ---------------- GEMM: C = A[M,768] * BT[N,768]^T, global_load_lds staging ----------------

template<int MODE>
__global__ __launch_bounds__(256) void gemm_bt(
    const uint16_t* __restrict__ Abf, const uint16_t* __restrict__ BTbf,
    const float* __restrict__ bias, float* __restrict__ outf,
    uint16_t* __restrict__ q_bf, uint16_t* __restrict__ k_bf,
    uint16_t* __restrict__ vT_bf) {
    __shared__ uint16_t As[128][32];
    __shared__ uint16_t Bs[128][32];
    const int t = threadIdx.x;
    const int lane = t & 63;
    const int w = t >> 6;
    const int wr = (w >> 1) * 64;
    const int wc = (w & 1) * 64;
    const int lr16 = lane & 15;
    const int lk = (lane >> 4) << 3;
    const size_t arow0 = (size_t)blockIdx.y * 128;
    const size_t brow0 = (size_t)blockIdx.x * 128;
    const int sr = lane >> 2;
    const int sc = (lane & 3) * 8;
    const uint16_t* Ap0 = Abf + (arow0 + w * 16 + sr) * NXC + sc;
    const uint16_t* Ap1 = Abf + (arow0 + 64 + w * 16 + sr) * NXC + sc;
    const uint16_t* Bp0 = BTbf + (brow0 + w * 16 + sr) * NXC + sc;
    const uint16_t* Bp1 = BTbf + (brow0 + 64 + w * 16 + sr) * NXC + sc;
    uint16_t* lA0 = &As[w * 16][0];
    uint16_t* lA1 = &As[64 + w * 16][0];
    uint16_t* lB0 = &Bs[w * 16][0];
    uint16_t* lB1 = &Bs[64 + w * 16][0];

    f32x4 acc[4][4];
#pragma unroll
    for (int m = 0; m < 4; ++m)
#pragma unroll
        for (int n = 0; n < 4; ++n) acc[m][n] = (f32x4){0.f, 0.f, 0.f, 0.f};

    for (int kt = 0; kt < 24; ++kt) {
        const int k0 = kt << 5;
        gload16(Ap0 + k0, lA0);
        gload16(Ap1 + k0, lA1);
        gload16(Bp0 + k0, lB0);
        gload16(Bp1 + k0, lB1);
        asm volatile("s_waitcnt vmcnt(0)" ::: "memory");
        __syncthreads();
        bf16x8 af[4], bv[4];
#pragma unroll
        for (int m = 0; m < 4; ++m) af[m] = *(const bf16x8*)&As[wr + m * 16 + lr16][lk];
#pragma unroll
        for (int n = 0; n < 4; ++n) bv[n] = *(const bf16x8*)&Bs[wc + n * 16 + lr16][lk];
#pragma unroll
        for (int m = 0; m < 4; ++m)
#pragma unroll
            for (int n = 0; n < 4; ++n)
                acc[m][n] = __builtin_amdgcn_mfma_f32_16x16x32_bf16(af[m], bv[n], acc[m][n], 0, 0, 0);
        __syncthreads();
    }

    const int rowb = (lane >> 4) << 2;
    const float QSCALE = 0.125f * 1.44269504f;   // fold 1/sqrt(dh) and log2(e)
#pragma unroll
    for (int m = 0; m < 4; ++m) {
        int grow0 = (int)arow0 + wr + m * 16 + rowb;
#pragma unroll
        for (int n = 0; n < 4; ++n) {
            int gcol = (int)brow0 + wc + n * 16 + lr16;
            float bvs = bias[gcol];
            if (MODE == 1) {
#pragma unroll
                for (int ri = 0; ri < 4; ++ri) {
                    int grow = grow0 + ri;
                    outf[(size_t)grow * NXC + gcol] = acc[m][n][ri] + bvs;
                }
            } else {
                int c = gcol >= 2 * NXC ? 2 : (gcol >= NXC ? 1 : 0);
                int e = gcol - c * NXC;
                int h = e >> 6, d = e & 63;
#pragma unroll
                for (int ri = 0; ri < 4; ++ri) {
                    int grow = grow0 + ri;
                    int b = grow >> 11, s = grow & 2047;
                    float v = acc[m][n][ri] + bvs;
                    size_t hidx = ((size_t)(b * NHEAD + h) * SS + s);
                    if (c == 0) {
                        q_bf[hidx * 64 + d] = f2bf(v * QSCALE);
                    } else if (c == 1) {
                        k_bf[hidx * 64 + d] = f2bf(v);
                        outf[hidx * 64 + d] = v;
                    } else {
                        vT_bf[((size_t)(b * NHEAD + h) * 64 + d) * SS + s] = f2bf(v);
                        outf[PRESENT_HALF + hidx * 64 + d] = v;
                    }
                }
            }
        }
    }
}

// ---------------- flash attention, LDS-staged K/V, swapped QK^T ----------------
// grid 768, block 128 (2 waves). Block = one 64-row q-block; wave w owns rows
// [qbase+32w, +32). Both waves share LDS-staged K/V tiles (64 keys), double-buffered.
// Staging: wave0->K, wave1->V via global_load_lds w/ inverse-XOR-swizzled source;
// reads use same XOR -> conflict-free. Softmax in log2 domain, defer-max.

__global__ __launch_bounds__(128) void attn_kernel(
    const uint16_t* __restrict__ qb, const uint16_t* __restrict__ kb,
    const uint16_t* __restrict__ vtb, uint16_t* __restrict__ ab) {
    __shared__ uint16_t KT[2][64][64];
    __shared__ uint16_t VT[2][64][64];
    const int t = threadIdx.x;
    const int w = t >> 6, lane = t & 63;
    const int l31 = lane & 31, hi = lane >> 5;
    const int i8 = lane >> 3, c8 = lane & 7;   // staging: row-in-8 / chunk
    const int id = blockIdx.x;
    const int xcd = id & 7, slot = id >> 3;    // 96 slots per xcd
    const int lh = slot % 3, qs = slot / 3;    // 3 heads/XCD, 32 q-blocks
    const int qi = 31 - qs;                    // heavy q-blocks first
    const int bh = xcd * 3 + lh;
    const int qbase = qi * 64;
    const int q = qbase + w * 32 + l31;
    const uint16_t* qh = qb + (size_t)bh * (SS * 64);
    const uint16_t* kh = kb + (size_t)bh * (SS * 64);
    const uint16_t* vh = vtb + (size_t)bh * (64 * SS);
    const int nkt = qi + 1;

    bf16x8 qf[4];
#pragma unroll
    for (int dc = 0; dc < 4; ++dc)
        qf[dc] = *(const bf16x8*)(qh + (size_t)q * 64 + dc * 16 + hi * 8);

    f32x16 o0, o1;
#pragma unroll
    for (int i = 0; i < 16; ++i) { o0[i] = 0.f; o1[i] = 0.f; }
    float m_run = -1e30f, l_run = 0.f;

    // staging sources (row = 8*jg + i8, chunk c8; source chunk = c8 ^ (row&7) = c8 ^ i8)
    const uint16_t* ksrc = kh + (size_t)i8 * 64 + ((c8 ^ i8) << 3);
    const uint16_t* vsrc = vh + (size_t)i8 * SS + ((c8 ^ i8) << 3);

    // prologue: stage tile 0 into buf 0
    if (w == 0) {
#pragma unroll
        for (int jg = 0; jg < 8; ++jg) gload16(ksrc + (size_t)jg * 8 * 64, &KT[0][jg * 8][0]);
    } else {
#pragma unroll
        for (int jg = 0; jg < 8; ++jg) gload16(vsrc + (size_t)jg * 8 * SS, &VT[0][jg * 8][0]);
    }
    asm volatile("s_waitcnt vmcnt(0)" ::: "memory");
    __syncthreads();

    int cur = 0;
    for (int kt = 0; kt < nkt; ++kt) {
        // stage next tile into buf^1 (overlaps with compute below)
        if (kt + 1 < nkt) {
            const int nb = (kt + 1) << 6;
            if (w == 0) {
#pragma unroll
                for (int jg = 0; jg < 8; ++jg)
                    gload16(ksrc + (size_t)(nb + jg * 8) * 64, &KT[cur ^ 1][jg * 8][0]);
            } else {
#pragma unroll
                for (int jg = 0; jg < 8; ++jg)
                    gload16(vsrc + (size_t)(jg * 8) * SS + nb, &VT[cur ^ 1][jg * 8][0]);
            }
        }
        const bool diag = (kt == qi);
        const bool doB = !diag || (w == 1);

        // QK^T: sa (keys 0..31), sb (keys 32..63); A = K rows from swizzled LDS
        f32x16 sa, sb;
#pragma unroll
        for (int i = 0; i < 16; ++i) { sa[i] = 0.f; sb[i] = 0.f; }
#pragma unroll
        for (int dc = 0; dc < 4; ++dc) {
            bf16x8 kfa = *(const bf16x8*)&KT[cur][l31][(((dc * 2 + hi) ^ (l31 & 7)) << 3)];
            sa = __builtin_amdgcn_mfma_f32_32x32x16_bf16(kfa, qf[dc], sa, 0, 0, 0);
        }
        if (doB) {
#pragma unroll
            for (int dc = 0; dc < 4; ++dc) {
                bf16x8 kfb = *(const bf16x8*)&KT[cur][32 + l31][(((dc * 2 + hi) ^ (l31 & 7)) << 3)];
                sb = __builtin_amdgcn_mfma_f32_32x32x16_bf16(kfb, qf[dc], sb, 0, 0, 0);
            }
        }
        // causal mask on the diagonal tile only
        if (diag) {
            if (w == 0) {
#pragma unroll
                for (int r = 0; r < 16; ++r) {
                    int key = (r & 3) + 8 * (r >> 2) + 4 * hi;
                    sa[r] = (key > l31) ? -1e30f : sa[r];
                }
            } else {
#pragma unroll
                for (int r = 0; r < 16; ++r) {
                    int key = 32 + (r & 3) + 8 * (r >> 2) + 4 * hi;
                    sb[r] = (key > 32 + l31) ? -1e30f : sb[r];
                }
            }
        }
        // row max: pairwise tree + cross-half exchange
        float mx4[4];
#pragma unroll
        for (int g = 0; g < 4; ++g)
            mx4[g] = fmaxf(fmaxf(sa[g * 4], sa[g * 4 + 1]), fmaxf(sa[g * 4 + 2], sa[g * 4 + 3]));
        float tm = fmaxf(fmaxf(mx4[0], mx4[1]), fmaxf(mx4[2], mx4[3]));
        if (doB) {
#pragma unroll
            for (int g = 0; g < 4; ++g)
                mx4[g] = fmaxf(fmaxf(sb[g * 4], sb[g * 4 + 1]), fmaxf(sb[g * 4 + 2], sb[g * 4 + 3]));
            tm = fmaxf(tm, fmaxf(fmaxf(mx4[0], mx4[1]), fmaxf(mx4[2], mx4[3])));
        }
        tm = fmaxf(tm, __shfl_xor(tm, 32));
        // defer-max (log2 domain)
        if (__any(tm > m_run + 8.f)) {
            float nm = fmaxf(m_run, tm);
            float corr = __builtin_amdgcn_exp2f(m_run - nm);
            l_run *= corr;
#pragma unroll
            for (int i = 0; i < 16; ++i) { o0[i] *= corr; o1[i] *= corr; }
            m_run = nm;
        }
        // exp + pack + sum
        float e[16];
#pragma unroll
        for (int r = 0; r < 16; ++r) e[r] = __builtin_amdgcn_exp2f(sa[r] - m_run);
        bf16x8 pa0, pa1;
#pragma unroll
        for (int r = 0; r < 8; ++r) { pa0[r] = (__bf16)e[r]; pa1[r] = (__bf16)e[8 + r]; }
        float ps = ((e[0] + e[1]) + (e[2] + e[3])) + ((e[4] + e[5]) + (e[6] + e[7]))
                 + ((e[8] + e[9]) + (e[10] + e[11])) + ((e[12] + e[13]) + (e[14] + e[15]));
        bf16x8 pb0, pb1;
        if (doB) {
#pragma unroll
            for (int r = 0; r < 16; ++r) e[r] = __builtin_amdgcn_exp2f(sb[r] - m_run);
#pragma unroll
            for (int r = 0; r < 8; ++r) { pb0[r] = (__bf16)e[r]; pb1[r] = (__bf16)e[8 + r]; }
            ps += ((e[0] + e[1]) + (e[2] + e[3])) + ((e[4] + e[5]) + (e[6] + e[7]))
                + ((e[8] + e[9]) + (e[10] + e[11])) + ((e[12] + e[13]) + (e[14] + e[15]));
        }
        ps += __shfl_xor(ps, 32);
        l_run += ps;
        // PV: V^T frags from swizzled LDS; chunk c holds source keys (c^(row&7))*8..+7
#pragma unroll
        for (int dblk = 0; dblk < 2; ++dblk) {
            const int row = dblk * 32 + l31;
            const int rx = l31 & 7;
            const uint16_t* vrow = &VT[cur][row][0];
            ushort4 v0 = *(const ushort4*)(vrow + ((0 ^ rx) << 3) + hi * 4);
            ushort4 v1 = *(const ushort4*)(vrow + ((1 ^ rx) << 3) + hi * 4);
            ushort4 v2 = *(const ushort4*)(vrow + ((2 ^ rx) << 3) + hi * 4);
            ushort4 v3 = *(const ushort4*)(vrow + ((3 ^ rx) << 3) + hi * 4);
            f32x16 oo = dblk ? o1 : o0;
            oo = __builtin_amdgcn_mfma_f32_32x32x16_bf16(vfrag(v0, v1), pa0, oo, 0, 0, 0);
            oo = __builtin_amdgcn_mfma_f32_32x32x16_bf16(vfrag(v2, v3), pa1, oo, 0, 0, 0);
            if (doB) {
                ushort4 v4 = *(const ushort4*)(vrow + ((4 ^ rx) << 3) + hi * 4);
                ushort4 v5 = *(const ushort4*)(vrow + ((5 ^ rx) << 3) + hi * 4);
                ushort4 v6 = *(const ushort4*)(vrow + ((6 ^ rx) << 3) + hi * 4);
                ushort4 v7 = *(const ushort4*)(vrow + ((7 ^ rx) << 3) + hi * 4);
                oo = __builtin_amdgcn_mfma_f32_32x32x16_bf16(vfrag(v4, v5), pb0, oo, 0, 0, 0);
                oo = __builtin_amdgcn_mfma_f32_32x32x16_bf16(vfrag(v6, v7), pb1, oo, 0, 0, 0);
            }
            if (dblk) o1 = oo; else o0 = oo;
        }
        asm volatile("s_waitcnt vmcnt(0)" ::: "memory");
        __syncthreads();
        cur ^= 1;
    }

    const float inv = 1.f / l_run;
    const int b = bh / NHEAD, h = bh - b * NHEAD;
    uint16_t* abp = ab + ((size_t)(b * SS + q)) * NXC + h * 64;
#pragma unroll
    for (int dblk = 0; dblk < 2; ++dblk)
#pragma unroll
        for (int rg = 0; rg < 4; ++rg) {
            f32x16 oo = dblk ? o1 : o0;
            ushort4 wv;
            wv.x = f2bf(oo[rg * 4 + 0] * inv);
            wv.y = f2bf(oo[rg * 4 + 1] * inv);
            wv.z = f2bf(oo[rg * 4 + 2] * inv);
            wv.w = f2bf(oo[rg * 4 + 3] * inv);
            *(ushort4*)(abp + dblk * 32 + rg * 8 + hi * 4) = wv;
        }
}

// ---------------- launch ----------------

extern "C" void kernel_launch(void* const* d_in, const int* in_sizes, int n_in,
                              void* d_out, int out_size, void* d_ws, size_t ws_size,
                              hipStream_t stream) {
    const float* x      = (const float*)d_in[0];
    const float* w_attn = (const float*)d_in[1];
    const float* b_attn = (const float*)d_in[2];
    const float* lora_A = (const float*)d_in[3];
    const float* lora_B = (const float*)d_in[4];
    const float* w_proj = (const float*)d_in[5];
    const float* b_proj = (const float*)d_in[6];
    float* out = (float*)d_out;
    float* present = out + (size_t)MTOT * NXC;   // 3145728

    uint16_t* ws    = (uint16_t*)d_ws;
    uint16_t* x_bf  = ws;                         // 3145728
    uint16_t* weffT = x_bf + 3145728;             // 1769472
    uint16_t* wpT   = weffT + 1769472;            // 589824
    uint16_t* q_bf  = wpT + 589824;               // 3145728
    uint16_t* k_bf  = q_bf + 3145728;             // 3145728
    uint16_t* vT_bf = k_bf + 3145728;             // 3145728
    uint16_t* a_bf  = vT_bf + 3145728;            // 3145728

    prep_x<<<dim3(3072), dim3(256), 0, stream>>>(x, x_bf);
    prep_weff<<<dim3(6912), dim3(256), 0, stream>>>(w_attn, lora_A, lora_B, weffT);
    prep_wproj<<<dim3(2304), dim3(256), 0, stream>>>(w_proj, wpT);

    gemm_bt<0><<<dim3(18, 32), dim3(256), 0, stream>>>(x_bf, weffT, b_attn, present,
                                                       q_bf, k_bf, vT_bf);
    attn_kernel<<<dim3(768), dim3(128), 0, stream>>>(q_bf, k_bf, vT_bf, a_bf);
    gemm_bt<1><<<dim3(6, 32), dim3(256), 0, stream>>>(a_bf, wpT, b_proj, out,
                                                      nullptr, nullptr, nullptr);
}

// Round 6
// 124.045 us; speedup vs baseline: 1.5092x; 1.0457x over previous
//
#include <hip/hip_runtime.h>
#include <cstdint>

#define NXC 768
#define NHEAD 12
#define BB 2
#define SS 2048
#define MTOT (BB*SS)        // 4096
#define NQKV (3*NXC)        // 2304
#define PRESENT_HALF (BB*NHEAD*SS*64)   // 3145728

typedef __bf16 bf16x8 __attribute__((ext_vector_type(8)));
typedef float f32x4 __attribute__((ext_vector_type(4)));
typedef float f32x16 __attribute__((ext_vector_type(16)));

__device__ __forceinline__ uint16_t f2bf(float f) {
    uint32_t u = __builtin_bit_cast(uint32_t, f);
    uint32_t r = (u + 0x7FFFu + ((u >> 16) & 1u)) >> 16;
    return (uint16_t)r;
}

__device__ __forceinline__ bf16x8 vfrag(ushort4 a, ushort4 b) {
    union { bf16x8 v; ushort4 u[2]; } r;
    r.u[0] = a; r.u[1] = b;
    return r.v;
}

// async global->LDS, 16B per lane; lds dest = wave-uniform base + lane*16
__device__ __forceinline__ void gload16(const uint16_t* g, uint16_t* l) {
    __builtin_amdgcn_global_load_lds(
        (const __attribute__((address_space(1))) unsigned int*)g,
        (__attribute__((address_space(3))) unsigned int*)l, 16, 0, 0);
}

// ---------------- prep kernels ----------------

__global__ void prep_x(const float* __restrict__ in, uint16_t* __restrict__ out) {
    int i = blockIdx.x * 256 + threadIdx.x;
    float4 v = ((const float4*)in)[i];
    ushort4 o;
    o.x = f2bf(v.x); o.y = f2bf(v.y); o.z = f2bf(v.z); o.w = f2bf(v.w);
    ((ushort4*)out)[i] = o;
}

// tiled transpose + LoRA fold: weffT[n][k] = w_attn[k][n] + 16*sum_r A[c,r,k]*B[n,r]
// grid (36, 12): block handles n-tile [bn*64,+64), k-tile [bk*64,+64)
__global__ __launch_bounds__(256) void prep_weff(const float* __restrict__ w_attn,
                          const float* __restrict__ lora_A,
                          const float* __restrict__ lora_B,
                          uint16_t* __restrict__ weffT) {
    __shared__ float T[64][65];
    __shared__ float Af[8][64];
    __shared__ float Bf[64][8];
    const int t = threadIdx.x;
    const int n0 = blockIdx.x * 64, k0 = blockIdx.y * 64;
    const int c = n0 / NXC;
    // coalesced read of w_attn[k][n] tile
    {
        const int nn = t & 63, q = t >> 6;
#pragma unroll
        for (int j = 0; j < 16; ++j) {
            int kr = q + j * 4;
            T[kr][nn] = w_attn[(size_t)(k0 + kr) * NQKV + n0 + nn];
        }
    }
    // LoRA slices (coalesced)
    {
        int idx = t;
        Af[idx >> 6][idx & 63] = lora_A[(size_t)(c * 8 + (idx >> 6)) * NXC + k0 + (idx & 63)];
        idx += 256;
        Af[idx >> 6][idx & 63] = lora_A[(size_t)(c * 8 + (idx >> 6)) * NXC + k0 + (idx & 63)];
        Bf[t >> 3][t & 7] = lora_B[(size_t)(n0 + (t >> 3)) * 8 + (t & 7)];
        idx = t + 256;
        Bf[idx >> 3][idx & 7] = lora_B[(size_t)(n0 + (idx >> 3)) * 8 + (idx & 7)];
    }
    __syncthreads();
    // compute + coalesced write of weffT[n][k]
    const int kk = t & 63, q = t >> 6;
#pragma unroll
    for (int j = 0; j < 16; ++j) {
        int nn = q + j * 4;
        float d = 0.f;
#pragma unroll
        for (int r = 0; r < 8; ++r) d += Af[r][kk] * Bf[nn][r];
        weffT[(size_t)(n0 + nn) * NXC + k0 + kk] = f2bf(T[kk][nn] + 16.0f * d);
    }
}

// tiled transpose: wpT[n][k] = w_proj[k][n]; grid (12, 12)
__global__ __launch_bounds__(256) void prep_wproj(const float* __restrict__ w_proj,
                                                  uint16_t* __restrict__ wpT) {
    __shared__ float T[64][65];
    const int t = threadIdx.x;
    const int n0 = blockIdx.x * 64, k0 = blockIdx.y * 64;
    {
        const int nn = t & 63, q = t >> 6;
#pragma unroll
        for (int j = 0; j < 16; ++j) {
            int kr = q + j * 4;
            T[kr][nn] = w_proj[(size_t)(k0 + kr) * NXC + n0 + nn];
        }
    }
    __syncthreads();
    const int kk = t & 63, q = t >> 6;
#pragma unroll
    for (int j = 0; j < 16; ++j) {
        int nn = q + j * 4;
        wpT[(size_t)(n0 + nn) * NXC + k0 + kk] = f2bf(T[kk][nn]);
    }
}

// ---------------- GEMM: C = A[M,768] * BT[N,768]^T, dbuf global_load_lds ----------------
// 4 waves, wave quadrant (BM/2, BN/2). MODE 0: qkv scatter epilogue; MODE 1: bias+f32 out.

template<int MODE, int BM, int BN>
__global__ __launch_bounds__(256) void gemm_bt(
    const uint16_t* __restrict__ Abf, const uint16_t* __restrict__ BTbf,
    const float* __restrict__ bias, float* __restrict__ outf,
    uint16_t* __restrict__ q_bf, uint16_t* __restrict__ k_bf,
    uint16_t* __restrict__ vT_bf) {
    constexpr int MR = BM / 32;
    constexpr int NR = BN / 32;
    __shared__ uint16_t As[2][BM][32];
    __shared__ uint16_t Bs[2][BN][32];
    const int t = threadIdx.x;
    const int lane = t & 63;
    const int w = t >> 6;
    const int wr = (w >> 1) * (BM / 2);
    const int wc = (w & 1) * (BN / 2);
    const int lr16 = lane & 15;
    const int lk = (lane >> 4) << 3;
    const size_t arow0 = (size_t)blockIdx.y * BM;
    const size_t brow0 = (size_t)blockIdx.x * BN;
    const int sr = lane >> 2;           // row within 16-row stage chunk
    const int sc = (lane & 3) * 8;      // col (8 bf16 = 16B)

    f32x4 acc[MR][NR];
#pragma unroll
    for (int m = 0; m < MR; ++m)
#pragma unroll
        for (int n = 0; n < NR; ++n) acc[m][n] = (f32x4){0.f, 0.f, 0.f, 0.f};

    // prologue: stage kt=0 into buf 0
#pragma unroll
    for (int i = 0; i < BM / 64; ++i)
        gload16(Abf + (arow0 + i * 64 + w * 16 + sr) * NXC + sc, &As[0][i * 64 + w * 16][0]);
#pragma unroll
    for (int i = 0; i < BN / 64; ++i)
        gload16(BTbf + (brow0 + i * 64 + w * 16 + sr) * NXC + sc, &Bs[0][i * 64 + w * 16][0]);
    asm volatile("s_waitcnt vmcnt(0)" ::: "memory");
    __syncthreads();

    int cur = 0;
    for (int kt = 0; kt < 24; ++kt) {
        const int k0n = (kt + 1) << 5;
        if (kt + 1 < 24) {
#pragma unroll
            for (int i = 0; i < BM / 64; ++i)
                gload16(Abf + (arow0 + i * 64 + w * 16 + sr) * NXC + k0n + sc,
                        &As[cur ^ 1][i * 64 + w * 16][0]);
#pragma unroll
            for (int i = 0; i < BN / 64; ++i)
                gload16(BTbf + (brow0 + i * 64 + w * 16 + sr) * NXC + k0n + sc,
                        &Bs[cur ^ 1][i * 64 + w * 16][0]);
        }
        bf16x8 af[MR], bv[NR];
#pragma unroll
        for (int m = 0; m < MR; ++m) af[m] = *(const bf16x8*)&As[cur][wr + m * 16 + lr16][lk];
#pragma unroll
        for (int n = 0; n < NR; ++n) bv[n] = *(const bf16x8*)&Bs[cur][wc + n * 16 + lr16][lk];
#pragma unroll
        for (int m = 0; m < MR; ++m)
#pragma unroll
            for (int n = 0; n < NR; ++n)
                acc[m][n] = __builtin_amdgcn_mfma_f32_16x16x32_bf16(af[m], bv[n], acc[m][n], 0, 0, 0);
        asm volatile("s_waitcnt vmcnt(0)" ::: "memory");
        __syncthreads();
        cur ^= 1;
    }

    const int rowb = (lane >> 4) << 2;
    const float QSCALE = 0.125f * 1.44269504f;   // fold 1/sqrt(dh) and log2(e)
#pragma unroll
    for (int m = 0; m < MR; ++m) {
        int grow0 = (int)arow0 + wr + m * 16 + rowb;
#pragma unroll
        for (int n = 0; n < NR; ++n) {
            int gcol = (int)brow0 + wc + n * 16 + lr16;
            float bvs = bias[gcol];
            if (MODE == 1) {
#pragma unroll
                for (int ri = 0; ri < 4; ++ri) {
                    int grow = grow0 + ri;
                    outf[(size_t)grow * NXC + gcol] = acc[m][n][ri] + bvs;
                }
            } else {
                int c = gcol >= 2 * NXC ? 2 : (gcol >= NXC ? 1 : 0);
                int e = gcol - c * NXC;
                int h = e >> 6, d = e & 63;
#pragma unroll
                for (int ri = 0; ri < 4; ++ri) {
                    int grow = grow0 + ri;
                    int b = grow >> 11, s = grow & 2047;
                    float v = acc[m][n][ri] + bvs;
                    size_t hidx = ((size_t)(b * NHEAD + h) * SS + s);
                    if (c == 0) {
                        q_bf[hidx * 64 + d] = f2bf(v * QSCALE);
                    } else if (c == 1) {
                        k_bf[hidx * 64 + d] = f2bf(v);
                        outf[hidx * 64 + d] = v;
                    } else {
                        vT_bf[((size_t)(b * NHEAD + h) * 64 + d) * SS + s] = f2bf(v);
                        outf[PRESENT_HALF + hidx * 64 + d] = v;
                    }
                }
            }
        }
    }
}

// ---------------- flash attention, LDS-staged K/V, swapped QK^T ----------------
// grid 768, block 128 (2 waves). Block = one 64-row q-block; wave w owns rows
// [qbase+32w, +32). Both waves share LDS-staged K/V tiles (64 keys), double-buffered.

__global__ __launch_bounds__(128) void attn_kernel(
    const uint16_t* __restrict__ qb, const uint16_t* __restrict__ kb,
    const uint16_t* __restrict__ vtb, uint16_t* __restrict__ ab) {
    __shared__ uint16_t KT[2][64][64];
    __shared__ uint16_t VT[2][64][64];
    const int t = threadIdx.x;
    const int w = t >> 6, lane = t & 63;
    const int l31 = lane & 31, hi = lane >> 5;
    const int i8 = lane >> 3, c8 = lane & 7;   // staging: row-in-8 / chunk
    const int id = blockIdx.x;
    const int xcd = id & 7, slot = id >> 3;    // 96 slots per xcd
    const int lh = slot % 3, qs = slot / 3;    // 3 heads/XCD, 32 q-blocks
    const int qi = 31 - qs;                    // heavy q-blocks first
    const int bh = xcd * 3 + lh;
    const int qbase = qi * 64;
    const int q = qbase + w * 32 + l31;
    const uint16_t* qh = qb + (size_t)bh * (SS * 64);
    const uint16_t* kh = kb + (size_t)bh * (SS * 64);
    const uint16_t* vh = vtb + (size_t)bh * (64 * SS);
    const int nkt = qi + 1;

    bf16x8 qf[4];
#pragma unroll
    for (int dc = 0; dc < 4; ++dc)
        qf[dc] = *(const bf16x8*)(qh + (size_t)q * 64 + dc * 16 + hi * 8);

    f32x16 o0, o1;
#pragma unroll
    for (int i = 0; i < 16; ++i) { o0[i] = 0.f; o1[i] = 0.f; }
    float m_run = -1e30f, l_run = 0.f;

    // staging sources (row = 8*jg + i8, chunk c8; source chunk = c8 ^ (row&7) = c8 ^ i8)
    const uint16_t* ksrc = kh + (size_t)i8 * 64 + ((c8 ^ i8) << 3);
    const uint16_t* vsrc = vh + (size_t)i8 * SS + ((c8 ^ i8) << 3);

    // prologue: stage tile 0 into buf 0
    if (w == 0) {
#pragma unroll
        for (int jg = 0; jg < 8; ++jg) gload16(ksrc + (size_t)jg * 8 * 64, &KT[0][jg * 8][0]);
    } else {
#pragma unroll
        for (int jg = 0; jg < 8; ++jg) gload16(vsrc + (size_t)jg * 8 * SS, &VT[0][jg * 8][0]);
    }
    asm volatile("s_waitcnt vmcnt(0)" ::: "memory");
    __syncthreads();

    int cur = 0;
    for (int kt = 0; kt < nkt; ++kt) {
        // stage next tile into buf^1 (overlaps with compute below)
        if (kt + 1 < nkt) {
            const int nb = (kt + 1) << 6;
            if (w == 0) {
#pragma unroll
                for (int jg = 0; jg < 8; ++jg)
                    gload16(ksrc + (size_t)(nb + jg * 8) * 64, &KT[cur ^ 1][jg * 8][0]);
            } else {
#pragma unroll
                for (int jg = 0; jg < 8; ++jg)
                    gload16(vsrc + (size_t)(jg * 8) * SS + nb, &VT[cur ^ 1][jg * 8][0]);
            }
        }
        const bool diag = (kt == qi);
        const bool doB = !diag || (w == 1);

        // QK^T: sa (keys 0..31), sb (keys 32..63); A = K rows from swizzled LDS
        f32x16 sa, sb;
#pragma unroll
        for (int i = 0; i < 16; ++i) { sa[i] = 0.f; sb[i] = 0.f; }
        __builtin_amdgcn_s_setprio(1);
#pragma unroll
        for (int dc = 0; dc < 4; ++dc) {
            bf16x8 kfa = *(const bf16x8*)&KT[cur][l31][(((dc * 2 + hi) ^ (l31 & 7)) << 3)];
            sa = __builtin_amdgcn_mfma_f32_32x32x16_bf16(kfa, qf[dc], sa, 0, 0, 0);
        }
        if (doB) {
#pragma unroll
            for (int dc = 0; dc < 4; ++dc) {
                bf16x8 kfb = *(const bf16x8*)&KT[cur][32 + l31][(((dc * 2 + hi) ^ (l31 & 7)) << 3)];
                sb = __builtin_amdgcn_mfma_f32_32x32x16_bf16(kfb, qf[dc], sb, 0, 0, 0);
            }
        }
        __builtin_amdgcn_s_setprio(0);
        // causal mask on the diagonal tile only
        if (diag) {
            if (w == 0) {
#pragma unroll
                for (int r = 0; r < 16; ++r) {
                    int key = (r & 3) + 8 * (r >> 2) + 4 * hi;
                    sa[r] = (key > l31) ? -1e30f : sa[r];
                }
            } else {
#pragma unroll
                for (int r = 0; r < 16; ++r) {
                    int key = 32 + (r & 3) + 8 * (r >> 2) + 4 * hi;
                    sb[r] = (key > 32 + l31) ? -1e30f : sb[r];
                }
            }
        }
        // row max: pairwise tree + cross-half exchange
        float mx4[4];
#pragma unroll
        for (int g = 0; g < 4; ++g)
            mx4[g] = fmaxf(fmaxf(sa[g * 4], sa[g * 4 + 1]), fmaxf(sa[g * 4 + 2], sa[g * 4 + 3]));
        float tm = fmaxf(fmaxf(mx4[0], mx4[1]), fmaxf(mx4[2], mx4[3]));
        if (doB) {
#pragma unroll
            for (int g = 0; g < 4; ++g)
                mx4[g] = fmaxf(fmaxf(sb[g * 4], sb[g * 4 + 1]), fmaxf(sb[g * 4 + 2], sb[g * 4 + 3]));
            tm = fmaxf(tm, fmaxf(fmaxf(mx4[0], mx4[1]), fmaxf(mx4[2], mx4[3])));
        }
        tm = fmaxf(tm, __shfl_xor(tm, 32));
        // defer-max (log2 domain)
        if (__any(tm > m_run + 8.f)) {
            float nm = fmaxf(m_run, tm);
            float corr = __builtin_amdgcn_exp2f(m_run - nm);
            l_run *= corr;
#pragma unroll
            for (int i = 0; i < 16; ++i) { o0[i] *= corr; o1[i] *= corr; }
            m_run = nm;
        }
        // exp + pack + sum
        float e[16];
#pragma unroll
        for (int r = 0; r < 16; ++r) e[r] = __builtin_amdgcn_exp2f(sa[r] - m_run);
        bf16x8 pa0, pa1;
#pragma unroll
        for (int r = 0; r < 8; ++r) { pa0[r] = (__bf16)e[r]; pa1[r] = (__bf16)e[8 + r]; }
        float ps = ((e[0] + e[1]) + (e[2] + e[3])) + ((e[4] + e[5]) + (e[6] + e[7]))
                 + ((e[8] + e[9]) + (e[10] + e[11])) + ((e[12] + e[13]) + (e[14] + e[15]));
        bf16x8 pb0, pb1;
        if (doB) {
#pragma unroll
            for (int r = 0; r < 16; ++r) e[r] = __builtin_amdgcn_exp2f(sb[r] - m_run);
#pragma unroll
            for (int r = 0; r < 8; ++r) { pb0[r] = (__bf16)e[r]; pb1[r] = (__bf16)e[8 + r]; }
            ps += ((e[0] + e[1]) + (e[2] + e[3])) + ((e[4] + e[5]) + (e[6] + e[7]))
                + ((e[8] + e[9]) + (e[10] + e[11])) + ((e[12] + e[13]) + (e[14] + e[15]));
        }
        ps += __shfl_xor(ps, 32);
        l_run += ps;
        // PV: V^T frags from swizzled LDS; chunk c holds source keys (c^(row&7))*8..+7
        __builtin_amdgcn_s_setprio(1);
#pragma unroll
        for (int dblk = 0; dblk < 2; ++dblk) {
            const int row = dblk * 32 + l31;
            const int rx = l31 & 7;
            const uint16_t* vrow = &VT[cur][row][0];
            ushort4 v0 = *(const ushort4*)(vrow + ((0 ^ rx) << 3) + hi * 4);
            ushort4 v1 = *(const ushort4*)(vrow + ((1 ^ rx) << 3) + hi * 4);
            ushort4 v2 = *(const ushort4*)(vrow + ((2 ^ rx) << 3) + hi * 4);
            ushort4 v3 = *(const ushort4*)(vrow + ((3 ^ rx) << 3) + hi * 4);
            f32x16 oo = dblk ? o1 : o0;
            oo = __builtin_amdgcn_mfma_f32_32x32x16_bf16(vfrag(v0, v1), pa0, oo, 0, 0, 0);
            oo = __builtin_amdgcn_mfma_f32_32x32x16_bf16(vfrag(v2, v3), pa1, oo, 0, 0, 0);
            if (doB) {
                ushort4 v4 = *(const ushort4*)(vrow + ((4 ^ rx) << 3) + hi * 4);
                ushort4 v5 = *(const ushort4*)(vrow + ((5 ^ rx) << 3) + hi * 4);
                ushort4 v6 = *(const ushort4*)(vrow + ((6 ^ rx) << 3) + hi * 4);
                ushort4 v7 = *(const ushort4*)(vrow + ((7 ^ rx) << 3) + hi * 4);
                oo = __builtin_amdgcn_mfma_f32_32x32x16_bf16(vfrag(v4, v5), pb0, oo, 0, 0, 0);
                oo = __builtin_amdgcn_mfma_f32_32x32x16_bf16(vfrag(v6, v7), pb1, oo, 0, 0, 0);
            }
            if (dblk) o1 = oo; else o0 = oo;
        }
        __builtin_amdgcn_s_setprio(0);
        asm volatile("s_waitcnt vmcnt(0)" ::: "memory");
        __syncthreads();
        cur ^= 1;
    }

    const float inv = 1.f / l_run;
    const int b = bh / NHEAD, h = bh - b * NHEAD;
    uint16_t* abp = ab + ((size_t)(b * SS + q)) * NXC + h * 64;
#pragma unroll
    for (int dblk = 0; dblk < 2; ++dblk)
#pragma unroll
        for (int rg = 0; rg < 4; ++rg) {
            f32x16 oo = dblk ? o1 : o0;
            ushort4 wv;
            wv.x = f2bf(oo[rg * 4 + 0] * inv);
            wv.y = f2bf(oo[rg * 4 + 1] * inv);
            wv.z = f2bf(oo[rg * 4 + 2] * inv);
            wv.w = f2bf(oo[rg * 4 + 3] * inv);
            *(ushort4*)(abp + dblk * 32 + rg * 8 + hi * 4) = wv;
        }
}

// ---------------- launch ----------------

extern "C" void kernel_launch(void* const* d_in, const int* in_sizes, int n_in,
                              void* d_out, int out_size, void* d_ws, size_t ws_size,
                              hipStream_t stream) {
    const float* x      = (const float*)d_in[0];
    const float* w_attn = (const float*)d_in[1];
    const float* b_attn = (const float*)d_in[2];
    const float* lora_A = (const float*)d_in[3];
    const float* lora_B = (const float*)d_in[4];
    const float* w_proj = (const float*)d_in[5];
    const float* b_proj = (const float*)d_in[6];
    float* out = (float*)d_out;
    float* present = out + (size_t)MTOT * NXC;   // 3145728

    uint16_t* ws    = (uint16_t*)d_ws;
    uint16_t* x_bf  = ws;                         // 3145728
    uint16_t* weffT = x_bf + 3145728;             // 1769472
    uint16_t* wpT   = weffT + 1769472;            // 589824
    uint16_t* q_bf  = wpT + 589824;               // 3145728
    uint16_t* k_bf  = q_bf + 3145728;             // 3145728
    uint16_t* vT_bf = k_bf + 3145728;             // 3145728
    uint16_t* a_bf  = vT_bf + 3145728;            // 3145728

    prep_x<<<dim3(3072), dim3(256), 0, stream>>>(x, x_bf);
    prep_weff<<<dim3(36, 12), dim3(256), 0, stream>>>(w_attn, lora_A, lora_B, weffT);
    prep_wproj<<<dim3(12, 12), dim3(256), 0, stream>>>(w_proj, wpT);

    gemm_bt<0, 128, 128><<<dim3(18, 32), dim3(256), 0, stream>>>(
        x_bf, weffT, b_attn, present, q_bf, k_bf, vT_bf);
    attn_kernel<<<dim3(768), dim3(128), 0, stream>>>(q_bf, k_bf, vT_bf, a_bf);
    gemm_bt<1, 128, 64><<<dim3(12, 32), dim3(256), 0, stream>>>(
        a_bf, wpT, b_proj, out, nullptr, nullptr, nullptr);
}

// Round 7
// 122.590 us; speedup vs baseline: 1.5271x; 1.0119x over previous
//
#include <hip/hip_runtime.h>
#include <cstdint>

#define NXC 768
#define NHEAD 12
#define BB 2
#define SS 2048
#define MTOT (BB*SS)        // 4096
#define NQKV (3*NXC)        // 2304
#define PRESENT_HALF (BB*NHEAD*SS*64)   // 3145728

typedef __bf16 bf16x8 __attribute__((ext_vector_type(8)));
typedef float f32x4 __attribute__((ext_vector_type(4)));
typedef float f32x16 __attribute__((ext_vector_type(16)));

__device__ __forceinline__ uint16_t f2bf(float f) {
    uint32_t u = __builtin_bit_cast(uint32_t, f);
    uint32_t r = (u + 0x7FFFu + ((u >> 16) & 1u)) >> 16;
    return (uint16_t)r;
}

__device__ __forceinline__ bf16x8 vfrag(ushort4 a, ushort4 b) {
    union { bf16x8 v; ushort4 u[2]; } r;
    r.u[0] = a; r.u[1] = b;
    return r.v;
}

// async global->LDS, 16B per lane; lds dest = wave-uniform base + lane*16
__device__ __forceinline__ void gload16(const uint16_t* g, uint16_t* l) {
    __builtin_amdgcn_global_load_lds(
        (const __attribute__((address_space(1))) unsigned int*)g,
        (__attribute__((address_space(3))) unsigned int*)l, 16, 0, 0);
}

// ---------------- prep kernels ----------------

__global__ void prep_x(const float* __restrict__ in, uint16_t* __restrict__ out) {
    int i = blockIdx.x * 256 + threadIdx.x;
    float4 v = ((const float4*)in)[i];
    ushort4 o;
    o.x = f2bf(v.x); o.y = f2bf(v.y); o.z = f2bf(v.z); o.w = f2bf(v.w);
    ((ushort4*)out)[i] = o;
}

// tiled transpose + LoRA fold: weffT[n][k] = w_attn[k][n] + 16*sum_r A[c,r,k]*B[n,r]
__global__ __launch_bounds__(256) void prep_weff(const float* __restrict__ w_attn,
                          const float* __restrict__ lora_A,
                          const float* __restrict__ lora_B,
                          uint16_t* __restrict__ weffT) {
    __shared__ float T[64][65];
    __shared__ float Af[8][64];
    __shared__ float Bf[64][8];
    const int t = threadIdx.x;
    const int n0 = blockIdx.x * 64, k0 = blockIdx.y * 64;
    const int c = n0 / NXC;
    {
        const int nn = t & 63, q = t >> 6;
#pragma unroll
        for (int j = 0; j < 16; ++j) {
            int kr = q + j * 4;
            T[kr][nn] = w_attn[(size_t)(k0 + kr) * NQKV + n0 + nn];
        }
    }
    {
        int idx = t;
        Af[idx >> 6][idx & 63] = lora_A[(size_t)(c * 8 + (idx >> 6)) * NXC + k0 + (idx & 63)];
        idx += 256;
        Af[idx >> 6][idx & 63] = lora_A[(size_t)(c * 8 + (idx >> 6)) * NXC + k0 + (idx & 63)];
        Bf[t >> 3][t & 7] = lora_B[(size_t)(n0 + (t >> 3)) * 8 + (t & 7)];
        idx = t + 256;
        Bf[idx >> 3][idx & 7] = lora_B[(size_t)(n0 + (idx >> 3)) * 8 + (idx & 7)];
    }
    __syncthreads();
    const int kk = t & 63, q = t >> 6;
#pragma unroll
    for (int j = 0; j < 16; ++j) {
        int nn = q + j * 4;
        float d = 0.f;
#pragma unroll
        for (int r = 0; r < 8; ++r) d += Af[r][kk] * Bf[nn][r];
        weffT[(size_t)(n0 + nn) * NXC + k0 + kk] = f2bf(T[kk][nn] + 16.0f * d);
    }
}

// tiled transpose: wpT[n][k] = w_proj[k][n]
__global__ __launch_bounds__(256) void prep_wproj(const float* __restrict__ w_proj,
                                                  uint16_t* __restrict__ wpT) {
    __shared__ float T[64][65];
    const int t = threadIdx.x;
    const int n0 = blockIdx.x * 64, k0 = blockIdx.y * 64;
    {
        const int nn = t & 63, q = t >> 6;
#pragma unroll
        for (int j = 0; j < 16; ++j) {
            int kr = q + j * 4;
            T[kr][nn] = w_proj[(size_t)(k0 + kr) * NXC + n0 + nn];
        }
    }
    __syncthreads();
    const int kk = t & 63, q = t >> 6;
#pragma unroll
    for (int j = 0; j < 16; ++j) {
        int nn = q + j * 4;
        wpT[(size_t)(n0 + nn) * NXC + k0 + kk] = f2bf(T[kk][nn]);
    }
}

// ---------------- GEMM: C = A[M,768] * BT[N,768]^T, dbuf global_load_lds ----------------
// 1-D grid with XCD swizzle: wgid = (id%8)*(nwg/8)+id/8; by = wgid/NBX (A-panel per XCD).

template<int MODE, int BM, int BN, int NBX>
__global__ __launch_bounds__(256) void gemm_bt(
    const uint16_t* __restrict__ Abf, const uint16_t* __restrict__ BTbf,
    const float* __restrict__ bias, float* __restrict__ outf,
    uint16_t* __restrict__ q_bf, uint16_t* __restrict__ k_bf,
    uint16_t* __restrict__ vT_bf) {
    constexpr int MR = BM / 32;
    constexpr int NR = BN / 32;
    __shared__ uint16_t As[2][BM][32];
    __shared__ uint16_t Bs[2][BN][32];
    const int t = threadIdx.x;
    const int lane = t & 63;
    const int w = t >> 6;
    const int wr = (w >> 1) * (BM / 2);
    const int wc = (w & 1) * (BN / 2);
    const int lr16 = lane & 15;
    const int lk = (lane >> 4) << 3;
    // XCD swizzle (bijective: gridDim.x % 8 == 0)
    const int id = blockIdx.x;
    const int wgid = (id & 7) * ((int)gridDim.x >> 3) + (id >> 3);
    const int by = wgid / NBX, bx = wgid - by * NBX;
    const size_t arow0 = (size_t)by * BM;
    const size_t brow0 = (size_t)bx * BN;
    const int sr = lane >> 2;           // row within 16-row stage chunk
    const int sc = (lane & 3) * 8;      // col (8 bf16 = 16B)

    f32x4 acc[MR][NR];
#pragma unroll
    for (int m = 0; m < MR; ++m)
#pragma unroll
        for (int n = 0; n < NR; ++n) acc[m][n] = (f32x4){0.f, 0.f, 0.f, 0.f};

    // prologue: stage kt=0 into buf 0
#pragma unroll
    for (int i = 0; i < BM / 64; ++i)
        gload16(Abf + (arow0 + i * 64 + w * 16 + sr) * NXC + sc, &As[0][i * 64 + w * 16][0]);
#pragma unroll
    for (int i = 0; i < BN / 64; ++i)
        gload16(BTbf + (brow0 + i * 64 + w * 16 + sr) * NXC + sc, &Bs[0][i * 64 + w * 16][0]);
    asm volatile("s_waitcnt vmcnt(0)" ::: "memory");
    __syncthreads();

    int cur = 0;
    for (int kt = 0; kt < 24; ++kt) {
        const int k0n = (kt + 1) << 5;
        if (kt + 1 < 24) {
#pragma unroll
            for (int i = 0; i < BM / 64; ++i)
                gload16(Abf + (arow0 + i * 64 + w * 16 + sr) * NXC + k0n + sc,
                        &As[cur ^ 1][i * 64 + w * 16][0]);
#pragma unroll
            for (int i = 0; i < BN / 64; ++i)
                gload16(BTbf + (brow0 + i * 64 + w * 16 + sr) * NXC + k0n + sc,
                        &Bs[cur ^ 1][i * 64 + w * 16][0]);
        }
        bf16x8 af[MR], bv[NR];
#pragma unroll
        for (int m = 0; m < MR; ++m) af[m] = *(const bf16x8*)&As[cur][wr + m * 16 + lr16][lk];
#pragma unroll
        for (int n = 0; n < NR; ++n) bv[n] = *(const bf16x8*)&Bs[cur][wc + n * 16 + lr16][lk];
#pragma unroll
        for (int m = 0; m < MR; ++m)
#pragma unroll
            for (int n = 0; n < NR; ++n)
                acc[m][n] = __builtin_amdgcn_mfma_f32_16x16x32_bf16(af[m], bv[n], acc[m][n], 0, 0, 0);
        asm volatile("s_waitcnt vmcnt(0)" ::: "memory");
        __syncthreads();
        cur ^= 1;
    }

    const int rowb = (lane >> 4) << 2;
    const float QSCALE = 0.125f * 1.44269504f;   // fold 1/sqrt(dh) and log2(e)
#pragma unroll
    for (int m = 0; m < MR; ++m) {
        int grow0 = (int)arow0 + wr + m * 16 + rowb;
#pragma unroll
        for (int n = 0; n < NR; ++n) {
            int gcol = (int)brow0 + wc + n * 16 + lr16;
            float bvs = bias[gcol];
            if (MODE == 1) {
#pragma unroll
                for (int ri = 0; ri < 4; ++ri) {
                    int grow = grow0 + ri;
                    outf[(size_t)grow * NXC + gcol] = acc[m][n][ri] + bvs;
                }
            } else {
                int c = gcol >= 2 * NXC ? 2 : (gcol >= NXC ? 1 : 0);
                int e = gcol - c * NXC;
                int h = e >> 6, d = e & 63;
#pragma unroll
                for (int ri = 0; ri < 4; ++ri) {
                    int grow = grow0 + ri;
                    int b = grow >> 11, s = grow & 2047;
                    float v = acc[m][n][ri] + bvs;
                    size_t hidx = ((size_t)(b * NHEAD + h) * SS + s);
                    if (c == 0) {
                        q_bf[hidx * 64 + d] = f2bf(v * QSCALE);
                    } else if (c == 1) {
                        k_bf[hidx * 64 + d] = f2bf(v);
                        outf[hidx * 64 + d] = v;
                    } else {
                        vT_bf[((size_t)(b * NHEAD + h) * 64 + d) * SS + s] = f2bf(v);
                        outf[PRESENT_HALF + hidx * 64 + d] = v;
                    }
                }
            }
        }
    }
}

// ---------------- flash attention, LDS-staged K/V, swapped QK^T (unchanged) ----------------

__global__ __launch_bounds__(128) void attn_kernel(
    const uint16_t* __restrict__ qb, const uint16_t* __restrict__ kb,
    const uint16_t* __restrict__ vtb, uint16_t* __restrict__ ab) {
    __shared__ uint16_t KT[2][64][64];
    __shared__ uint16_t VT[2][64][64];
    const int t = threadIdx.x;
    const int w = t >> 6, lane = t & 63;
    const int l31 = lane & 31, hi = lane >> 5;
    const int i8 = lane >> 3, c8 = lane & 7;   // staging: row-in-8 / chunk
    const int id = blockIdx.x;
    const int xcd = id & 7, slot = id >> 3;    // 96 slots per xcd
    const int lh = slot % 3, qs = slot / 3;    // 3 heads/XCD, 32 q-blocks
    const int qi = 31 - qs;                    // heavy q-blocks first
    const int bh = xcd * 3 + lh;
    const int qbase = qi * 64;
    const int q = qbase + w * 32 + l31;
    const uint16_t* qh = qb + (size_t)bh * (SS * 64);
    const uint16_t* kh = kb + (size_t)bh * (SS * 64);
    const uint16_t* vh = vtb + (size_t)bh * (64 * SS);
    const int nkt = qi + 1;

    bf16x8 qf[4];
#pragma unroll
    for (int dc = 0; dc < 4; ++dc)
        qf[dc] = *(const bf16x8*)(qh + (size_t)q * 64 + dc * 16 + hi * 8);

    f32x16 o0, o1;
#pragma unroll
    for (int i = 0; i < 16; ++i) { o0[i] = 0.f; o1[i] = 0.f; }
    float m_run = -1e30f, l_run = 0.f;

    // staging sources (row = 8*jg + i8, chunk c8; source chunk = c8 ^ (row&7) = c8 ^ i8)
    const uint16_t* ksrc = kh + (size_t)i8 * 64 + ((c8 ^ i8) << 3);
    const uint16_t* vsrc = vh + (size_t)i8 * SS + ((c8 ^ i8) << 3);

    // prologue: stage tile 0 into buf 0
    if (w == 0) {
#pragma unroll
        for (int jg = 0; jg < 8; ++jg) gload16(ksrc + (size_t)jg * 8 * 64, &KT[0][jg * 8][0]);
    } else {
#pragma unroll
        for (int jg = 0; jg < 8; ++jg) gload16(vsrc + (size_t)jg * 8 * SS, &VT[0][jg * 8][0]);
    }
    asm volatile("s_waitcnt vmcnt(0)" ::: "memory");
    __syncthreads();

    int cur = 0;
    for (int kt = 0; kt < nkt; ++kt) {
        // stage next tile into buf^1 (overlaps with compute below)
        if (kt + 1 < nkt) {
            const int nb = (kt + 1) << 6;
            if (w == 0) {
#pragma unroll
                for (int jg = 0; jg < 8; ++jg)
                    gload16(ksrc + (size_t)(nb + jg * 8) * 64, &KT[cur ^ 1][jg * 8][0]);
            } else {
#pragma unroll
                for (int jg = 0; jg < 8; ++jg)
                    gload16(vsrc + (size_t)(jg * 8) * SS + nb, &VT[cur ^ 1][jg * 8][0]);
            }
        }
        const bool diag = (kt == qi);
        const bool doB = !diag || (w == 1);

        // QK^T: sa (keys 0..31), sb (keys 32..63); A = K rows from swizzled LDS
        f32x16 sa, sb;
#pragma unroll
        for (int i = 0; i < 16; ++i) { sa[i] = 0.f; sb[i] = 0.f; }
        __builtin_amdgcn_s_setprio(1);
#pragma unroll
        for (int dc = 0; dc < 4; ++dc) {
            bf16x8 kfa = *(const bf16x8*)&KT[cur][l31][(((dc * 2 + hi) ^ (l31 & 7)) << 3)];
            sa = __builtin_amdgcn_mfma_f32_32x32x16_bf16(kfa, qf[dc], sa, 0, 0, 0);
        }
        if (doB) {
#pragma unroll
            for (int dc = 0; dc < 4; ++dc) {
                bf16x8 kfb = *(const bf16x8*)&KT[cur][32 + l31][(((dc * 2 + hi) ^ (l31 & 7)) << 3)];
                sb = __builtin_amdgcn_mfma_f32_32x32x16_bf16(kfb, qf[dc], sb, 0, 0, 0);
            }
        }
        __builtin_amdgcn_s_setprio(0);
        // causal mask on the diagonal tile only
        if (diag) {
            if (w == 0) {
#pragma unroll
                for (int r = 0; r < 16; ++r) {
                    int key = (r & 3) + 8 * (r >> 2) + 4 * hi;
                    sa[r] = (key > l31) ? -1e30f : sa[r];
                }
            } else {
#pragma unroll
                for (int r = 0; r < 16; ++r) {
                    int key = 32 + (r & 3) + 8 * (r >> 2) + 4 * hi;
                    sb[r] = (key > 32 + l31) ? -1e30f : sb[r];
                }
            }
        }
        // row max: pairwise tree + cross-half exchange
        float mx4[4];
#pragma unroll
        for (int g = 0; g < 4; ++g)
            mx4[g] = fmaxf(fmaxf(sa[g * 4], sa[g * 4 + 1]), fmaxf(sa[g * 4 + 2], sa[g * 4 + 3]));
        float tm = fmaxf(fmaxf(mx4[0], mx4[1]), fmaxf(mx4[2], mx4[3]));
        if (doB) {
#pragma unroll
            for (int g = 0; g < 4; ++g)
                mx4[g] = fmaxf(fmaxf(sb[g * 4], sb[g * 4 + 1]), fmaxf(sb[g * 4 + 2], sb[g * 4 + 3]));
            tm = fmaxf(tm, fmaxf(fmaxf(mx4[0], mx4[1]), fmaxf(mx4[2], mx4[3])));
        }
        tm = fmaxf(tm, __shfl_xor(tm, 32));
        // defer-max (log2 domain)
        if (__any(tm > m_run + 8.f)) {
            float nm = fmaxf(m_run, tm);
            float corr = __builtin_amdgcn_exp2f(m_run - nm);
            l_run *= corr;
#pragma unroll
            for (int i = 0; i < 16; ++i) { o0[i] *= corr; o1[i] *= corr; }
            m_run = nm;
        }
        // exp + pack + sum
        float e[16];
#pragma unroll
        for (int r = 0; r < 16; ++r) e[r] = __builtin_amdgcn_exp2f(sa[r] - m_run);
        bf16x8 pa0, pa1;
#pragma unroll
        for (int r = 0; r < 8; ++r) { pa0[r] = (__bf16)e[r]; pa1[r] = (__bf16)e[8 + r]; }
        float ps = ((e[0] + e[1]) + (e[2] + e[3])) + ((e[4] + e[5]) + (e[6] + e[7]))
                 + ((e[8] + e[9]) + (e[10] + e[11])) + ((e[12] + e[13]) + (e[14] + e[15]));
        bf16x8 pb0, pb1;
        if (doB) {
#pragma unroll
            for (int r = 0; r < 16; ++r) e[r] = __builtin_amdgcn_exp2f(sb[r] - m_run);
#pragma unroll
            for (int r = 0; r < 8; ++r) { pb0[r] = (__bf16)e[r]; pb1[r] = (__bf16)e[8 + r]; }
            ps += ((e[0] + e[1]) + (e[2] + e[3])) + ((e[4] + e[5]) + (e[6] + e[7]))
                + ((e[8] + e[9]) + (e[10] + e[11])) + ((e[12] + e[13]) + (e[14] + e[15]));
        }
        ps += __shfl_xor(ps, 32);
        l_run += ps;
        // PV: V^T frags from swizzled LDS; chunk c holds source keys (c^(row&7))*8..+7
        __builtin_amdgcn_s_setprio(1);
#pragma unroll
        for (int dblk = 0; dblk < 2; ++dblk) {
            const int row = dblk * 32 + l31;
            const int rx = l31 & 7;
            const uint16_t* vrow = &VT[cur][row][0];
            ushort4 v0 = *(const ushort4*)(vrow + ((0 ^ rx) << 3) + hi * 4);
            ushort4 v1 = *(const ushort4*)(vrow + ((1 ^ rx) << 3) + hi * 4);
            ushort4 v2 = *(const ushort4*)(vrow + ((2 ^ rx) << 3) + hi * 4);
            ushort4 v3 = *(const ushort4*)(vrow + ((3 ^ rx) << 3) + hi * 4);
            f32x16 oo = dblk ? o1 : o0;
            oo = __builtin_amdgcn_mfma_f32_32x32x16_bf16(vfrag(v0, v1), pa0, oo, 0, 0, 0);
            oo = __builtin_amdgcn_mfma_f32_32x32x16_bf16(vfrag(v2, v3), pa1, oo, 0, 0, 0);
            if (doB) {
                ushort4 v4 = *(const ushort4*)(vrow + ((4 ^ rx) << 3) + hi * 4);
                ushort4 v5 = *(const ushort4*)(vrow + ((5 ^ rx) << 3) + hi * 4);
                ushort4 v6 = *(const ushort4*)(vrow + ((6 ^ rx) << 3) + hi * 4);
                ushort4 v7 = *(const ushort4*)(vrow + ((7 ^ rx) << 3) + hi * 4);
                oo = __builtin_amdgcn_mfma_f32_32x32x16_bf16(vfrag(v4, v5), pb0, oo, 0, 0, 0);
                oo = __builtin_amdgcn_mfma_f32_32x32x16_bf16(vfrag(v6, v7), pb1, oo, 0, 0, 0);
            }
            if (dblk) o1 = oo; else o0 = oo;
        }
        __builtin_amdgcn_s_setprio(0);
        asm volatile("s_waitcnt vmcnt(0)" ::: "memory");
        __syncthreads();
        cur ^= 1;
    }

    const float inv = 1.f / l_run;
    const int b = bh / NHEAD, h = bh - b * NHEAD;
    uint16_t* abp = ab + ((size_t)(b * SS + q)) * NXC + h * 64;
#pragma unroll
    for (int dblk = 0; dblk < 2; ++dblk)
#pragma unroll
        for (int rg = 0; rg < 4; ++rg) {
            f32x16 oo = dblk ? o1 : o0;
            ushort4 wv;
            wv.x = f2bf(oo[rg * 4 + 0] * inv);
            wv.y = f2bf(oo[rg * 4 + 1] * inv);
            wv.z = f2bf(oo[rg * 4 + 2] * inv);
            wv.w = f2bf(oo[rg * 4 + 3] * inv);
            *(ushort4*)(abp + dblk * 32 + rg * 8 + hi * 4) = wv;
        }
}

// ---------------- launch ----------------

extern "C" void kernel_launch(void* const* d_in, const int* in_sizes, int n_in,
                              void* d_out, int out_size, void* d_ws, size_t ws_size,
                              hipStream_t stream) {
    const float* x      = (const float*)d_in[0];
    const float* w_attn = (const float*)d_in[1];
    const float* b_attn = (const float*)d_in[2];
    const float* lora_A = (const float*)d_in[3];
    const float* lora_B = (const float*)d_in[4];
    const float* w_proj = (const float*)d_in[5];
    const float* b_proj = (const float*)d_in[6];
    float* out = (float*)d_out;
    float* present = out + (size_t)MTOT * NXC;   // 3145728

    uint16_t* ws    = (uint16_t*)d_ws;
    uint16_t* x_bf  = ws;                         // 3145728
    uint16_t* weffT = x_bf + 3145728;             // 1769472
    uint16_t* wpT   = weffT + 1769472;            // 589824
    uint16_t* q_bf  = wpT + 589824;               // 3145728
    uint16_t* k_bf  = q_bf + 3145728;             // 3145728
    uint16_t* vT_bf = k_bf + 3145728;             // 3145728
    uint16_t* a_bf  = vT_bf + 3145728;            // 3145728

    prep_x<<<dim3(3072), dim3(256), 0, stream>>>(x, x_bf);
    prep_weff<<<dim3(36, 12), dim3(256), 0, stream>>>(w_attn, lora_A, lora_B, weffT);
    prep_wproj<<<dim3(12, 12), dim3(256), 0, stream>>>(w_proj, wpT);

    // gemm0: 4096x2304, BM=128 BN=64 -> 32*36 = 1152 blocks (XCD-swizzled internally)
    gemm_bt<0, 128, 64, 36><<<dim3(1152), dim3(256), 0, stream>>>(
        x_bf, weffT, b_attn, present, q_bf, k_bf, vT_bf);
    attn_kernel<<<dim3(768), dim3(128), 0, stream>>>(q_bf, k_bf, vT_bf, a_bf);
    // gemm1: 4096x768, BM=128 BN=64 -> 32*12 = 384 blocks
    gemm_bt<1, 128, 64, 12><<<dim3(384), dim3(256), 0, stream>>>(
        a_bf, wpT, b_proj, out, nullptr, nullptr, nullptr);
}